// Round 9
// baseline (1704.211 us; speedup 1.0000x reference)
//
#include <hip/hip_runtime.h>
#include <hip/hip_bf16.h>

#define DEV static __device__ __forceinline__

typedef short short8 __attribute__((ext_vector_type(8)));
typedef short short4v __attribute__((ext_vector_type(4)));
typedef float f32x4 __attribute__((ext_vector_type(4)));

#define NB 512
#define SL 256
#define ED 300
#define HD 200
#define EP 320   // padded embed stride (shorts)
#define HP 224   // padded hidden stride
#define TSP 236  // LDS layer-1 output tile stride (236: lane bank-starts all distinct)
#define GSTR 53248   // per-(b,side) Gt size in shorts: 208*256

DEV short f2b(float f){ __hip_bfloat16 h = __float2bfloat16(f); short s; __builtin_memcpy(&s,&h,2); return s; }

// ---------- one-time conversions ----------
__global__ __launch_bounds__(256) void conv_emb(const float* __restrict__ src, short* __restrict__ dst){
  size_t g = (size_t)blockIdx.x*256 + threadIdx.x;
  if (g >= (size_t)50000*EP) return;
  int row = (int)(g/EP), k = (int)(g%EP);
  dst[g] = (k<ED) ? f2b(src[(size_t)row*ED + k]) : (short)0;
}
// Wt[n][k] (208 x KP) <- W[k][n] (Kreal x 200), zero padded
__global__ __launch_bounds__(256) void convT_plain(const float* __restrict__ W, short* __restrict__ Wt,
                                                   int Kreal, int KP){
  int g = blockIdx.x*256 + threadIdx.x;
  if (g >= 208*KP) return;
  int n = g/KP, k = g%KP;
  float v = (n<HD && k<Kreal) ? W[(size_t)k*HD + n] : 0.f;
  Wt[g] = f2b(v);
}

// ---------- fused 2-layer attend MLP: direct global->reg->MFMA, LDS only for Ts ----------
__global__ __launch_bounds__(256) void mlp2(
    const short* __restrict__ embb,
    const int* __restrict__ idxA, const int* __restrict__ idxB,
    const short* __restrict__ W1t, const float* __restrict__ b1,
    const short* __restrict__ W2t, const float* __restrict__ b2,
    short* __restrict__ OutA, short* __restrict__ OutB)
{
  __shared__ __align__(16) short Ts[64*TSP];
  const int tid=threadIdx.x, lane=tid&63, w=tid>>6, quad=lane>>4, ln=lane&15;
  const int half = gridDim.x>>1;
  const int side = (blockIdx.x >= half) ? 1 : 0;
  const int row0 = (blockIdx.x - side*half)*64;
  const int* idx = side ? idxB : idxA;
  const int myRow = idx[row0 + w*16 + ln];
  const short* A0 = embb + (size_t)myRow*EP + quad*8;

  f32x4 acc[13];
  #pragma unroll
  for (int t=0;t<13;t++) acc[t]=(f32x4){0.f,0.f,0.f,0.f};

  // ---- layer 1 (K=320, 10 steps), no LDS, no barriers ----
  for (int ks=0; ks<10; ks++){
    short8 aR = *(const short8*)(A0 + ks*32);
    short8 bT[13];
    #pragma unroll
    for (int t=0;t<13;t++)
      bT[t] = *(const short8*)&W1t[(size_t)(t*16+ln)*EP + ks*32 + quad*8];
    #pragma unroll
    for (int t=0;t<13;t++)
      acc[t] = __builtin_amdgcn_mfma_f32_16x16x32_bf16(aR, bT[t], acc[t], 0,0,0);
  }
  // layer-1 epilogue -> Ts (+ zero cols 208..223)
  #pragma unroll
  for (int t=0;t<13;t++){
    int col = t*16+ln;
    float bv = (col<HD) ? b1[col] : 0.f;
    #pragma unroll
    for (int r=0;r<4;r++){
      int rl = w*16+quad*4+r;
      float v = (col<HD) ? fmaxf(acc[t][r]+bv, 0.f) : 0.f;
      Ts[rl*TSP + col] = f2b(v);
    }
    acc[t]=(f32x4){0.f,0.f,0.f,0.f};
  }
  if (tid < 128){ int r=tid>>1, c=tid&1;
    short8 z = {0,0,0,0,0,0,0,0};
    *(short8*)&Ts[r*TSP + 208 + c*8] = z; }
  __syncthreads();

  // ---- layer 2 (K=224, 7 steps): A from Ts, B direct ----
  for (int ks=0; ks<7; ks++){
    short8 aR = *(const short8*)&Ts[(w*16+ln)*TSP + ks*32 + quad*8];
    short8 bT[13];
    #pragma unroll
    for (int t=0;t<13;t++)
      bT[t] = *(const short8*)&W2t[(size_t)(t*16+ln)*HP + ks*32 + quad*8];
    #pragma unroll
    for (int t=0;t<13;t++)
      acc[t] = __builtin_amdgcn_mfma_f32_16x16x32_bf16(aR, bT[t], acc[t], 0,0,0);
  }
  short* Out = side ? OutB : OutA;
  #pragma unroll
  for (int t=0;t<13;t++){
    int col = t*16+ln;
    float bv = (col<HD) ? b2[col] : 0.f;
    #pragma unroll
    for (int r=0;r<4;r++){
      int rl = w*16+quad*4+r;
      float v = (col<HD) ? fmaxf(acc[t][r]+bv, 0.f) : 0.f;
      Out[(size_t)(row0+rl)*HP + col] = f2b(v);
    }
  }
  if (tid < 128){ int r=tid>>1, c=tid&1;
    short8 z = {0,0,0,0,0,0,0,0};
    *(short8*)&Out[(size_t)(row0+r)*HP + 208 + c*8] = z; }
}

// ---------- scores + fused row/col max (e >= 0 since h >= 0): fully LDS-free ----------
__global__ __launch_bounds__(256) void scores_gemm(
    const short* __restrict__ h1, const short* __restrict__ h2, float* __restrict__ e,
    unsigned* __restrict__ RmU, unsigned* __restrict__ CmU)
{
  const int b = blockIdx.z;
  const int i0 = blockIdx.x*64, j0 = blockIdx.y*64;
  const int tid=threadIdx.x, lane=tid&63, w=tid>>6, quad=lane>>4, ln=lane&15;
  f32x4 acc[4];
  #pragma unroll
  for (int t=0;t<4;t++) acc[t]=(f32x4){0.f,0.f,0.f,0.f};
  const short* Abase = h1 + ((size_t)b*SL + i0 + w*16 + ln)*HP + quad*8;
  const short* Bbase = h2 + ((size_t)b*SL + j0)*HP + quad*8;
  for (int ks=0; ks<7; ks++){
    short8 aR = *(const short8*)(Abase + ks*32);
    short8 bT[4];
    #pragma unroll
    for (int t=0;t<4;t++)
      bT[t] = *(const short8*)(Bbase + (size_t)(t*16+ln)*HP + ks*32);
    #pragma unroll
    for (int t=0;t<4;t++)
      acc[t] = __builtin_amdgcn_mfma_f32_16x16x32_bf16(aR, bT[t], acc[t], 0,0,0);
  }
  #pragma unroll
  for (int t=0;t<4;t++){
    int j = j0 + t*16 + ln;
    #pragma unroll
    for (int r=0;r<4;r++){
      int i = i0 + w*16 + quad*4 + r;
      e[(size_t)b*SL*SL + (size_t)i*SL + j] = acc[t][r];
    }
  }
  // row maxes (over j)
  #pragma unroll
  for (int r=0;r<4;r++){
    float m = fmaxf(fmaxf(acc[0][r],acc[1][r]), fmaxf(acc[2][r],acc[3][r]));
    m=fmaxf(m,__shfl_xor(m,1)); m=fmaxf(m,__shfl_xor(m,2));
    m=fmaxf(m,__shfl_xor(m,4)); m=fmaxf(m,__shfl_xor(m,8));
    if (ln==0) atomicMax(&RmU[b*SL + i0 + w*16 + quad*4 + r], __float_as_uint(m));
  }
  // col maxes (over i)
  #pragma unroll
  for (int t=0;t<4;t++){
    float m = fmaxf(fmaxf(acc[t][0],acc[t][1]), fmaxf(acc[t][2],acc[t][3]));
    m=fmaxf(m,__shfl_xor(m,16)); m=fmaxf(m,__shfl_xor(m,32));
    if (quad==0) atomicMax(&CmU[b*SL + j0 + t*16 + ln], __float_as_uint(m));
  }
}

// ---------- P weights, normalized + masked + row-zeroed ----------
__global__ __launch_bounds__(256) void pwrite_k(
    const float* __restrict__ e, const unsigned* __restrict__ RmU, const unsigned* __restrict__ CmU,
    const int* __restrict__ len1, const int* __restrict__ len2,
    short* __restrict__ Pa, short* __restrict__ Pb)
{
  const int b = blockIdx.z, s = blockIdx.x, ori = blockIdx.y;
  const float* eb = e + (size_t)b*SL*SL;
  const int tid = threadIdx.x, lane = tid&63, w = tid>>6;
  if (ori == 0){
    const int l1 = len1[b], l2 = len2[b];
    for (int t=0;t<16;t++){
      int i = s*64 + w*16 + t;
      float cm = __uint_as_float(CmU[b*SL+i]);
      float4 v = ((const float4*)(eb + (size_t)i*SL))[lane];
      int c0 = lane*4;
      float e0 = (c0+0<l2) ? __expf(fminf(v.x-cm,85.f)) : 0.f;
      float e1 = (c0+1<l2) ? __expf(fminf(v.y-cm,85.f)) : 0.f;
      float e2 = (c0+2<l2) ? __expf(fminf(v.z-cm,85.f)) : 0.f;
      float e3 = (c0+3<l2) ? __expf(fminf(v.w-cm,85.f)) : 0.f;
      float ss = e0+e1+e2+e3;
      ss+=__shfl_xor(ss,1); ss+=__shfl_xor(ss,2); ss+=__shfl_xor(ss,4);
      ss+=__shfl_xor(ss,8); ss+=__shfl_xor(ss,16); ss+=__shfl_xor(ss,32);
      float inv = (ss>0.f && i<l1) ? 1.f/ss : 0.f;   // i>=l1: zero row (mask1 on betas)
      short4v o; o[0]=f2b(e0*inv); o[1]=f2b(e1*inv); o[2]=f2b(e2*inv); o[3]=f2b(e3*inv);
      ((short4v*)(Pb + (size_t)b*SL*SL + (size_t)i*SL))[lane] = o;
    }
  } else {
    __shared__ float Part[4][64];
    __shared__ float SaInv[64];
    __shared__ float RmS[64];
    __shared__ float Tile[64][65];
    const int l1 = len1[b], l2 = len2[b];
    const int j0 = s*64;
    if (tid < 64) RmS[tid] = __uint_as_float(RmU[b*SL + j0 + tid]);
    __syncthreads();
    {
      float sum = 0.f;
      for (int i=w; i<SL; i+=4)
        if (i < l1) sum += __expf(fminf(eb[(size_t)i*SL + j0 + lane] - RmS[lane], 85.f));
      Part[w][lane] = sum;
    }
    __syncthreads();
    if (w==0){
      float s_ = Part[0][lane]+Part[1][lane]+Part[2][lane]+Part[3][lane];
      SaInv[lane] = (s_>0.f && (j0+lane)<l2) ? 1.f/s_ : 0.f;  // j>=l2: zero row (mask2 on alphas)
    }
    __syncthreads();
    for (int ti=0; ti<4; ti++){
      const int i0 = ti*64;
      #pragma unroll 4
      for (int it=0; it<16; it++){
        int il = it*4 + w;
        int i = i0 + il;
        float v = eb[(size_t)i*SL + j0 + lane];
        float p = (i<l1) ? __expf(fminf(v - RmS[lane],85.f))*SaInv[lane] : 0.f;
        Tile[il][lane] = p;
      }
      __syncthreads();
      {
        int jl = tid>>2, q = tid&3;
        short8 o1, o2;
        #pragma unroll
        for (int u=0;u<8;u++){
          o1[u] = f2b(Tile[q*16+u][jl]);
          o2[u] = f2b(Tile[q*16+8+u][jl]);
        }
        short* dst = Pa + (size_t)b*SL*SL + (size_t)(j0+jl)*SL + i0 + q*16;
        *(short8*)dst = o1;
        *(short8*)(dst+8) = o2;
      }
      __syncthreads();
    }
  }
}

// ---------- ggemm: Gt[n][k] = sum_d embb[idx[k]][d] * W1cb[n][d]; direct loads, LDS only for transpose ----------
__global__ __launch_bounds__(256) void ggemm(
    const short* __restrict__ embb, const int* __restrict__ s1c, const int* __restrict__ s2c,
    const short* __restrict__ W1bt, short* __restrict__ G1t, short* __restrict__ G2t, int nbc)
{
  __shared__ __align__(16) short U[208*64];
  const int tid=threadIdx.x, lane=tid&63, w=tid>>6, quad=lane>>4, ln=lane&15;
  const int spp = 4*nbc;
  const int side = (blockIdx.x >= spp) ? 1 : 0;
  int lin = blockIdx.x - side*spp;
  int b, rb;
  if (nbc >= 8){ int sup=lin>>5, rem=lin&31; rb=rem>>3; b=sup*8+(rem&7); }
  else { b = lin>>2; rb = lin&3; }
  const int* idx = side ? s2c : s1c;
  short* Gt = (side ? G2t : G1t) + (size_t)b*GSTR;
  const int krow0 = rb*64;
  const int myRow = idx[b*SL + krow0 + w*16 + ln];
  const short* A0 = embb + (size_t)myRow*EP + quad*8;

  f32x4 acc[13];
  #pragma unroll
  for (int t=0;t<13;t++) acc[t]=(f32x4){0.f,0.f,0.f,0.f};
  for (int ks=0; ks<10; ks++){
    short8 aR = *(const short8*)(A0 + ks*32);
    short8 bT[13];
    #pragma unroll
    for (int t=0;t<13;t++)
      bT[t] = *(const short8*)&W1bt[(size_t)(t*16+ln)*EP + ks*32 + quad*8];
    #pragma unroll
    for (int t=0;t<13;t++)
      acc[t] = __builtin_amdgcn_mfma_f32_16x16x32_bf16(aR, bT[t], acc[t], 0,0,0);
  }
  // epilogue: XOR-swizzled LDS transpose (octet o of row n stored at o^(n&7))
  #pragma unroll
  for (int t=0;t<13;t++){
    int n = t*16+ln;
    #pragma unroll
    for (int r=0;r<4;r++){
      int kl = w*16+quad*4+r;
      int po = ((kl>>3) ^ (n&7));
      U[n*64 + po*8 + (kl&7)] = f2b(acc[t][r]);
    }
  }
  __syncthreads();
  #pragma unroll
  for (int it=0; it<7; it++){
    int p = it*256+tid, n = p>>3, oct = p&7;
    if (n < 208){
      short8 v = *(const short8*)&U[n*64 + (oct^(n&7))*8];
      *(short8*)&Gt[(size_t)n*SL + krow0 + oct*8] = v;
    }
  }
}

// ---------- compare MLP: layer1 = emb@W1cTop (K=320) + P@Gt (K=256), then layer2 + masked sum ----------
__global__ __launch_bounds__(256) void mlp2c(
    const short* __restrict__ embb,
    const int* __restrict__ s1c, const int* __restrict__ s2c,
    const short* __restrict__ Pb, const short* __restrict__ Pa,
    const short* __restrict__ G2t, const short* __restrict__ G1t,
    const short* __restrict__ W1tT, const float* __restrict__ b1,
    const short* __restrict__ W2t, const float* __restrict__ b2,
    const int* __restrict__ len1, const int* __restrict__ len2,
    float* __restrict__ v1, float* __restrict__ v2, int nbc)
{
  __shared__ __align__(16) short Ts[64*TSP];
  const int tid=threadIdx.x, lane=tid&63, w=tid>>6, quad=lane>>4, ln=lane&15;
  const int spp = 4*nbc;
  const int side = (blockIdx.x >= spp) ? 1 : 0;
  int lin = blockIdx.x - side*spp;
  int b, rb;
  if (nbc >= 8){ int sup=lin>>5, rem=lin&31; rb=rem>>3; b=sup*8+(rem&7); }
  else { b = lin>>2; rb = lin&3; }
  const int prow0 = rb*64;
  const int* idx = side ? s2c : s1c;
  const short* P = (side ? Pa : Pb) + (size_t)b*SL*SL;
  const short* Gt = (side ? G1t : G2t) + (size_t)b*GSTR;
  const int* lenArr = side ? len2 : len1;
  float* V = side ? v2 : v1;
  const int myRow = idx[b*SL + prow0 + w*16 + ln];
  const short* Aebase = embb + (size_t)myRow*EP + quad*8;
  const short* Apbase = P + (size_t)(prow0 + w*16 + ln)*SL + quad*8;

  f32x4 acc[13];
  #pragma unroll
  for (int t=0;t<13;t++) acc[t]=(f32x4){0.f,0.f,0.f,0.f};

  // ---- layer 1 phase A: e-part (K=320) ----
  for (int ks=0; ks<10; ks++){
    short8 aR = *(const short8*)(Aebase + ks*32);
    short8 bT[13];
    #pragma unroll
    for (int t=0;t<13;t++)
      bT[t] = *(const short8*)&W1tT[(size_t)(t*16+ln)*EP + ks*32 + quad*8];
    #pragma unroll
    for (int t=0;t<13;t++)
      acc[t] = __builtin_amdgcn_mfma_f32_16x16x32_bf16(aR, bT[t], acc[t], 0,0,0);
  }
  // ---- layer 1 phase B: P-part (K=256) ----
  for (int ks=0; ks<8; ks++){
    short8 aR = *(const short8*)(Apbase + ks*32);
    short8 bT[13];
    #pragma unroll
    for (int t=0;t<13;t++)
      bT[t] = *(const short8*)&Gt[(size_t)(t*16+ln)*SL + ks*32 + quad*8];
    #pragma unroll
    for (int t=0;t<13;t++)
      acc[t] = __builtin_amdgcn_mfma_f32_16x16x32_bf16(aR, bT[t], acc[t], 0,0,0);
  }
  // bias + relu -> Ts (+ zero cols 208..223)
  #pragma unroll
  for (int t=0;t<13;t++){
    int col = t*16+ln;
    float bv = (col<HD) ? b1[col] : 0.f;
    #pragma unroll
    for (int r=0;r<4;r++){
      int rl = w*16+quad*4+r;
      float v = (col<HD) ? fmaxf(acc[t][r]+bv, 0.f) : 0.f;
      Ts[rl*TSP + col] = f2b(v);
    }
    acc[t]=(f32x4){0.f,0.f,0.f,0.f};
  }
  if (tid < 128){ int r=tid>>1, c=tid&1;
    short8 z = {0,0,0,0,0,0,0,0};
    *(short8*)&Ts[r*TSP + 208 + c*8] = z; }
  __syncthreads();

  // ---- layer 2 (K=224) ----
  for (int ks=0; ks<7; ks++){
    short8 aR = *(const short8*)&Ts[(w*16+ln)*TSP + ks*32 + quad*8];
    short8 bT[13];
    #pragma unroll
    for (int t=0;t<13;t++)
      bT[t] = *(const short8*)&W2t[(size_t)(t*16+ln)*HP + ks*32 + quad*8];
    #pragma unroll
    for (int t=0;t<13;t++)
      acc[t] = __builtin_amdgcn_mfma_f32_16x16x32_bf16(aR, bT[t], acc[t], 0,0,0);
  }
  // masked row-sum epilogue
  {
    const int lenv = lenArr[b];
    const int posBase = prow0 + w*16 + quad*4;
    #pragma unroll
    for (int t=0;t<13;t++){
      int col = t*16+ln;
      float bv = (col<HD) ? b2[col] : 0.f;
      float s = 0.f;
      #pragma unroll
      for (int r=0;r<4;r++){
        float v = fmaxf(acc[t][r]+bv, 0.f);
        if (posBase + r < lenv) s += v;
      }
      s += __shfl_xor(s,16);
      s += __shfl_xor(s,32);
      if (quad==0 && col<HD) atomicAdd(&V[b*HD+col], s);
    }
  }
}

// ---------- aggregate ----------
__global__ __launch_bounds__(256) void aggregate(
    const float* __restrict__ v1, const float* __restrict__ v2,
    const float* __restrict__ W1g, const float* __restrict__ b1g,
    const float* __restrict__ W2g, const float* __restrict__ b2g,
    float* __restrict__ out)
{
  __shared__ float z[2*HD];
  __shared__ float a[HD];
  const int b = blockIdx.x, t = threadIdx.x;
  if (t < HD){ z[t] = v1[b*HD+t]; z[HD+t] = v2[b*HD+t]; }
  __syncthreads();
  if (t < HD){
    float acc = b1g[t];
    for (int k=0;k<2*HD;k++) acc += z[k]*W1g[(size_t)k*HD+t];
    a[t] = fmaxf(acc, 0.f);
  }
  __syncthreads();
  if (t < 2){
    float acc = b2g[t];
    for (int k=0;k<HD;k++) acc += a[k]*W2g[k*2+t];
    out[b*2+t] = acc;
  }
}

extern "C" void kernel_launch(void* const* d_in, const int* in_sizes, int n_in,
                              void* d_out, int out_size, void* d_ws, size_t ws_size,
                              hipStream_t stream) {
  const float* emb = (const float*)d_in[0];
  const float* W1a = (const float*)d_in[1];  const float* b1a = (const float*)d_in[2];
  const float* W2a = (const float*)d_in[3];  const float* b2a = (const float*)d_in[4];
  const float* W1c = (const float*)d_in[5];  const float* b1c = (const float*)d_in[6];
  const float* W2c = (const float*)d_in[7];  const float* b2c = (const float*)d_in[8];
  const float* W1g = (const float*)d_in[9];  const float* b1g = (const float*)d_in[10];
  const float* W2g = (const float*)d_in[11]; const float* b2g = (const float*)d_in[12];
  const int* s1 = (const int*)d_in[13];
  const int* s2 = (const int*)d_in[14];
  const int* len1 = (const int*)d_in[15];
  const int* len2 = (const int*)d_in[16];
  float* out = (float*)d_out;
  char* W = (char*)d_ws;

  // ---- fixed region ----
  float* v1    = (float*)(W);                      // 409,600
  float* v2    = (float*)(W + 409600);             // 409,600
  short* embb  = (short*)(W + 819200);             // 32,000,000
  short* W1at  = (short*)(W + 32819200);           // 133,120
  short* W2at  = (short*)(W + 32952320);           //  93,184
  short* W1ctT = (short*)(W + 33045504);           // 133,120
  short* W1cbT = (short*)(W + 33178624);           // 133,120
  short* W2ct  = (short*)(W + 33311744);           //  93,184
  char*  C0    = W + 33404928;
  const size_t FIXED = 33404928ull;

  // ---- per-batch chunked region ----
  const size_t PERB = 968704ull;
  int nbc = NB;
  while (nbc > 1 && FIXED + (size_t)nbc*PERB > ws_size) nbc >>= 1;
  const size_t nb = (size_t)nbc;
  short*    h1  = (short*)(C0);
  short*    h2  = (short*)(C0 + nb*114688);
  float*    e   = (float*)(C0 + nb*229376);
  short*    Pa  = (short*)(C0 + nb*491520);
  short*    Pb  = (short*)(C0 + nb*622592);
  short*    G1t = (short*)(C0 + nb*753664);
  short*    G2t = (short*)(C0 + nb*860160);
  unsigned* Rm  = (unsigned*)(C0 + nb*966656);
  unsigned* Cm  = (unsigned*)(C0 + nb*967680);

  const dim3 blk(256);
  hipMemsetAsync(v1, 0, 2ull*NB*HD*sizeof(float), stream);
  conv_emb<<<dim3((50000*EP+255)/256), blk, 0, stream>>>(emb, embb);
  convT_plain<<<dim3((208*EP+255)/256), blk, 0, stream>>>(W1a, W1at, ED, EP);
  convT_plain<<<dim3((208*HP+255)/256), blk, 0, stream>>>(W2a, W2at, HD, HP);
  convT_plain<<<dim3((208*EP+255)/256), blk, 0, stream>>>(W1c, W1ctT, ED, EP);
  convT_plain<<<dim3((208*EP+255)/256), blk, 0, stream>>>(W1c + (size_t)ED*HD, W1cbT, ED, EP);
  convT_plain<<<dim3((208*HP+255)/256), blk, 0, stream>>>(W2c, W2ct, HD, HP);

  const int chunks = NB / nbc;
  for (int c = 0; c < chunks; c++){
    const int b0 = c * nbc;
    const int* s1c = s1 + (size_t)b0*SL;
    const int* s2c = s2 + (size_t)b0*SL;
    const int* l1c = len1 + b0;
    const int* l2c = len2 + b0;

    hipMemsetAsync(Rm, 0, (size_t)nbc*SL*8, stream);   // Rm + Cm (contiguous), e>=0 so 0 is -inf
    mlp2<<<dim3(8*nbc), blk, 0, stream>>>(embb, s1c, s2c, W1at, b1a, W2at, b2a, h1, h2);
    scores_gemm<<<dim3(4,4,nbc), blk, 0, stream>>>(h1, h2, e, Rm, Cm);
    pwrite_k<<<dim3(4,2,nbc), blk, 0, stream>>>(e, Rm, Cm, l1c, l2c, Pa, Pb);
    ggemm<<<dim3(8*nbc), blk, 0, stream>>>(embb, s1c, s2c, W1cbT, G1t, G2t, nbc);
    mlp2c<<<dim3(8*nbc), blk, 0, stream>>>(embb, s1c, s2c, Pb, Pa, G2t, G1t,
                                           W1ctT, b1c, W2ct, b2c, l1c, l2c,
                                           v1 + (size_t)b0*HD, v2 + (size_t)b0*HD, nbc);
  }
  aggregate<<<dim3(NB), blk, 0, stream>>>(v1, v2, W1g, b1g, W2g, b2g, out);
}